// Round 1
// 307.015 us; speedup vs baseline: 1.1104x; 1.1104x over previous
//
#include <hip/hip_runtime.h>

// 6-level 2D DB4 wavelet (forward -> soft threshold -> inverse), N=4096 fp32.
// R3: multi-output threads + register sliding windows.
//   - fwd: float4 tile load, ds_read_b128 row-filter windows (4 outputs/item),
//          14-row col-filter window (4 outputs/thread).
//   - inv: parity divergence removed (each thread computes n=4q..4q+3 from a
//          6-row window), float4 coefficient loads, float4 output stores.
// LDS <= 40 KB in both kernels -> 4 blocks/CU. 13 launches total (unchanged).
//
// d_out layout: [0 .. 16777216) reconstruction, [16777216 .. 33554432) flat coeffs.
// Flat per level: row i = [hh_i | hl_i | lh_i], row stride 3*sc; final thr(approx)
// (64x64) at the tail.
//
// ws layout (floats): approx chain A1..A6 [0 .. 5591040) | P0 (4194304) | P1 (4194304)

__device__ __forceinline__ float thrf(float t, float alpha, float bp, float bm) {
    float s1 = 1.0f / (1.0f + __expf(-alpha * (t - bp)));
    float s2 = 1.0f / (1.0f + __expf( alpha * (t + bm)));
    return t * (s1 + s2);
}

__device__ __forceinline__ void load_filt(const float* __restrict__ filt,
                                          float (&h)[8], float (&w)[8]) {
#pragma unroll
    for (int k = 0; k < 8; ++k) h[k] = filt[k];
#pragma unroll
    for (int k = 0; k < 8; ++k) w[k] = (k & 1) ? -h[7 - k] : h[7 - k];
}

// Fused forward level: X (s x s) -> thresholded hh|hl|lh into flat (stride 3*sh)
// + raw ll into All (stride sh). 32x32 output tile per block, 256 threads.
// xs[rr][cc] = X[(2*i0-7+rr)&sm][(2*j0-8+cc)&sm]  (col base shifted to -8 for
// float4 alignment; filter taps re-derived for the shifted layout).
__global__ __launch_bounds__(256) void fwd_fused(
    const float* __restrict__ X, int s, int sh,
    float* __restrict__ flat, float* __restrict__ All,
    const float* __restrict__ filt_row, const float* __restrict__ filt_col,
    const float* __restrict__ ap, const float* __restrict__ bpp,
    const float* __restrict__ bmp) {
    __shared__ __align__(16) float xs[70][72];   // 20160 B
    __shared__ __align__(16) float Ds[70][36];   // 10080 B
    __shared__ __align__(16) float As[70][36];   // 10080 B  -> 40320 B total
    const int tid = threadIdx.x;
    const int j0 = blockIdx.x * 32, i0 = blockIdx.y * 32;
    float hr[8], wr[8], hc[8], wc[8];
    load_filt(filt_row, hr, wr);
    load_filt(filt_col, hc, wc);
    const int sm = s - 1;

    // stage 1: global -> LDS, float4 chunks (aligned: 2*j0-8+4c is mult of 4,
    // s mult of 4 so no wrap straddle).
    for (int idx = tid; idx < 70 * 18; idx += 256) {
        int rr = idx / 18, c = idx - rr * 18;
        int gr = (2 * i0 - 7 + rr) & sm;
        int gc = (2 * j0 - 8 + 4 * c) & sm;
        *(float4*)&xs[rr][4 * c] = *(const float4*)&X[(size_t)gr * s + gc];
    }
    __syncthreads();

    // stage 2: row filter. Item (rr,q) computes D/A for j=4q..4q+3 from one
    // 16-float window (4x ds_read_b128).  d(j) = sum_u wr[7-u]*xs[rr][2j+1+u].
    for (int idx = tid; idx < 70 * 8; idx += 256) {
        int rr = idx >> 3, q = idx & 7;
        const float4* xr = (const float4*)&xs[rr][8 * q];
        float wv[16];
#pragma unroll
        for (int m = 0; m < 4; ++m) {
            float4 t = xr[m];
            wv[4 * m + 0] = t.x; wv[4 * m + 1] = t.y;
            wv[4 * m + 2] = t.z; wv[4 * m + 3] = t.w;
        }
        float d[4], a[4];
#pragma unroll
        for (int e = 0; e < 4; ++e) {
            float dd = 0.f, aa = 0.f;
#pragma unroll
            for (int u = 0; u < 8; ++u) {
                float v = wv[2 * e + 1 + u];
                dd += wr[7 - u] * v;
                aa += hr[7 - u] * v;
            }
            d[e] = dd; a[e] = aa;
        }
        *(float4*)&Ds[rr][4 * q] = make_float4(d[0], d[1], d[2], d[3]);
        *(float4*)&As[rr][4 * q] = make_float4(a[0], a[1], a[2], a[3]);
    }
    __syncthreads();

    const float alpha = *ap, bp = *bpp, bm = *bmp;
    // stage 3: col filter + threshold. Thread (iq,j) computes outputs
    // i = 4iq..4iq+3 from a 14-row window.  hh(i) = sum_u wc[7-u]*D[2i+u][j].
    {
        const int j = tid & 31, iq = tid >> 5;
        float Dw[14], Aw[14];
#pragma unroll
        for (int t = 0; t < 14; ++t) {
            Dw[t] = Ds[8 * iq + t][j];
            Aw[t] = As[8 * iq + t][j];
        }
#pragma unroll
        for (int e = 0; e < 4; ++e) {
            float hh = 0.f, hl = 0.f, lh = 0.f, ll = 0.f;
#pragma unroll
            for (int u = 0; u < 8; ++u) {
                float dv = Dw[2 * e + u], av = Aw[2 * e + u];
                hh += wc[7 - u] * dv;
                hl += hc[7 - u] * dv;
                lh += wc[7 - u] * av;
                ll += hc[7 - u] * av;
            }
            int row = i0 + 4 * iq + e;
            size_t ro = (size_t)row * (3 * sh) + (j0 + j);
            flat[ro]           = thrf(hh, alpha, bp, bm);
            flat[ro + sh]      = thrf(hl, alpha, bp, bm);
            flat[ro + 2 * sh]  = thrf(lh, alpha, bp, bm);
            All[(size_t)row * sh + (j0 + j)] = ll;
        }
    }
}

__global__ void thr_kernel(const float* __restrict__ in, float* __restrict__ out,
                           int n, const float* __restrict__ ap,
                           const float* __restrict__ bpp,
                           const float* __restrict__ bmp) {
    int idx = blockIdx.x * blockDim.x + threadIdx.x;
    if (idx >= n) return;
    out[idx] = thrf(in[idx], *ap, *bpp, *bmp);
}

// Fused inverse level: hh|hl|lh from flat (stride 3*sc) + a (stride astride)
// -> out tile 64x64 full-res (stride ostride). 256 threads.
// Divergence-free: each thread computes all four parities n=4q..4q+3 (cols
// m=4p..4p+3) from a 6-row (6-col) register window.
__global__ __launch_bounds__(256) void inv_fused(
    const float* __restrict__ flatl, const float* __restrict__ a, int astride,
    int sc, float* __restrict__ outp, int ostride,
    const float* __restrict__ filt_col, const float* __restrict__ filt_row) {
    __shared__ __align__(16) float hhs[36][36], hls[36][36], lhs[36][36], as_[36][36]; // 20736 B
    __shared__ __align__(16) float Hs[64][36], Ls[64][36];                              // 18432 B -> 39168 B
    const int tid = threadIdx.x;
    const int m0 = blockIdx.x * 64, i0 = blockIdx.y * 64;
    float hr[8], wr[8], hc[8], wc[8];
    load_filt(filt_row, hr, wr);
    load_filt(filt_col, hc, wc);
    const int mm = sc - 1;
    const int r0 = i0 >> 1, c0 = m0 >> 1;
    const int ds = 3 * sc;

    // stage 1: load 36x36 tiles of all four coefficient arrays as float4 chunks.
    for (int idx = tid; idx < 4 * 324; idx += 256) {
        int aid = idx / 324, rem = idx - aid * 324;
        int rr = rem / 9, c = rem - rr * 9;
        int gr = (r0 + rr) & mm;
        int gc = (c0 + 4 * c) & mm;
        if (aid == 0)
            *(float4*)&hhs[rr][4 * c] = *(const float4*)&flatl[(size_t)gr * ds + gc];
        else if (aid == 1)
            *(float4*)&hls[rr][4 * c] = *(const float4*)&flatl[(size_t)gr * ds + sc + gc];
        else if (aid == 2)
            *(float4*)&lhs[rr][4 * c] = *(const float4*)&flatl[(size_t)gr * ds + 2 * sc + gc];
        else
            *(float4*)&as_[rr][4 * c] = *(const float4*)&a[(size_t)gr * astride + gc];
    }
    __syncthreads();

    // stage 2: col inverse. Item (q,jj) computes H/L rows n=4q..4q+3 from a
    // 6-row window (rows 2q..2q+5) -- no parity branches.
    for (int idx = tid; idx < 16 * 36; idx += 256) {
        int q = idx / 36, jj = idx - q * 36;
        float hv[6], lv[6], gv[6], av[6];
#pragma unroll
        for (int d = 0; d < 6; ++d) {
            int lr = 2 * q + d;
            hv[d] = hhs[lr][jj];
            lv[d] = hls[lr][jj];
            gv[d] = lhs[lr][jj];
            av[d] = as_[lr][jj];
        }
        float H0 = 0.f, H1 = 0.f, H2 = 0.f, H3 = 0.f;
        float L0 = 0.f, L1 = 0.f, L2 = 0.f, L3 = 0.f;
#pragma unroll
        for (int t = 0; t < 4; ++t) {
            float we = wc[2 * t], he = hc[2 * t];
            float wo = wc[2 * t + 1], ho = hc[2 * t + 1];
            H0 += we * hv[t]     + he * lv[t];
            H1 += wo * hv[t + 1] + ho * lv[t + 1];
            H2 += we * hv[t + 1] + he * lv[t + 1];
            H3 += wo * hv[t + 2] + ho * lv[t + 2];
            L0 += we * gv[t]     + he * av[t];
            L1 += wo * gv[t + 1] + ho * av[t + 1];
            L2 += we * gv[t + 1] + he * av[t + 1];
            L3 += wo * gv[t + 2] + ho * av[t + 2];
        }
        Hs[4 * q + 0][jj] = H0; Hs[4 * q + 1][jj] = H1;
        Hs[4 * q + 2][jj] = H2; Hs[4 * q + 3][jj] = H3;
        Ls[4 * q + 0][jj] = L0; Ls[4 * q + 1][jj] = L1;
        Ls[4 * q + 2][jj] = L2; Ls[4 * q + 3][jj] = L3;
    }
    __syncthreads();

    // stage 3: row inverse. Item (i,p) computes outputs m=4p..4p+3 from a
    // 6-col window (float2 reads), one float4 store.
    for (int idx = tid; idx < 64 * 16; idx += 256) {
        int i = idx >> 4, p = idx & 15;
        const float2* hp = (const float2*)&Hs[i][2 * p];
        const float2* lp = (const float2*)&Ls[i][2 * p];
        float2 hA = hp[0], hB = hp[1], hC = hp[2];
        float2 lA = lp[0], lB = lp[1], lC = lp[2];
        float Hw[6] = {hA.x, hA.y, hB.x, hB.y, hC.x, hC.y};
        float Lw[6] = {lA.x, lA.y, lB.x, lB.y, lC.x, lC.y};
        float o0 = 0.f, o1 = 0.f, o2 = 0.f, o3 = 0.f;
#pragma unroll
        for (int t = 0; t < 4; ++t) {
            float we = wr[2 * t], he = hr[2 * t];
            float wo = wr[2 * t + 1], ho = hr[2 * t + 1];
            o0 += we * Hw[t]     + he * Lw[t];
            o1 += wo * Hw[t + 1] + ho * Lw[t + 1];
            o2 += we * Hw[t + 1] + he * Lw[t + 1];
            o3 += wo * Hw[t + 2] + ho * Lw[t + 2];
        }
        *(float4*)&outp[(size_t)(i0 + i) * ostride + (m0 + 4 * p)] =
            make_float4(o0, o1, o2, o3);
    }
}

extern "C" void kernel_launch(void* const* d_in, const int* in_sizes, int n_in,
                              void* d_out, int out_size, void* d_ws, size_t ws_size,
                              hipStream_t stream) {
    const float* x    = (const float*)d_in[0];
    const float* scal = (const float*)d_in[1];  // 12 x 8
    const float* ap   = (const float*)d_in[2];
    const float* bp   = (const float*)d_in[3];
    const float* bm   = (const float*)d_in[4];
    float* out = (float*)d_out;
    float* ws  = (float*)d_ws;

    const int N = 4096;
    float* recon = out;
    float* flat  = out + 16777216;

    // ws offsets (floats)
    static const size_t Aoff[7] = {0, 0, 4194304, 5242880, 5505024, 5570560, 5586944};
    static const size_t flatOff[6] = {0, 12582912, 15728640, 16515072, 16711680, 16760832};
    const size_t finalOff = 16773120;
    float* P0 = ws + 5591040;
    float* P1 = ws + 5591040 + 4194304;

    dim3 blk(256);

    // ---------------- Forward (6 fused kernels) ----------------
    const float* src = x;
    for (int lev = 0; lev < 6; ++lev) {
        int s = N >> lev, sh = s >> 1;
        dim3 g(sh / 32, sh / 32);
        fwd_fused<<<g, blk, 0, stream>>>(src, s, sh, flat + flatOff[lev],
                                         ws + Aoff[lev + 1],
                                         scal + lev * 8, scal + (lev + 1) * 8,
                                         ap, bp, bm);
        src = ws + Aoff[lev + 1];
    }
    // threshold final approx (64x64) into flat tail
    thr_kernel<<<dim3(16), blk, 0, stream>>>(ws + Aoff[6], flat + finalOff, 4096,
                                             ap, bp, bm);

    // ---------------- Inverse (6 fused kernels) ----------------
    const float* a_in = flat + finalOff;
    for (int lev = 5; lev >= 0; --lev) {
        int sc = N >> (lev + 1), r = 2 * sc;
        float* outp = (lev == 0) ? recon : ((lev & 1) ? P1 : P0);
        dim3 g(r / 64, r / 64);
        inv_fused<<<g, blk, 0, stream>>>(flat + flatOff[lev], a_in, sc,
                                         sc, outp, r,
                                         scal + (lev + 1) * 8, scal + lev * 8);
        a_in = outp;
    }
}